// Round 8
// baseline (161.288 us; speedup 1.0000x reference)
//
#include <hip/hip_runtime.h>
#include <hip/hip_bf16.h>
#include <math.h>

#define BGRAPH 512
#define NNODE  100
#define EPG    1600
#define DIM    128
#define ETOT   (BGRAPH * EPG)   // 819200
#define PAD    132              // monolith fallback row stride
#define K1     80
#define K2     64

// d_ws layout (split path)
#define OFF_W    0ULL                      // whi 65536 + wlo 65536
#define OFF_AHL  131072ULL                 // per-graph 65536: hhi 32768 | hlo 32768 ; hnew f32 overlay
#define OFF_AB   (131072ULL + 33554432ULL) // per-graph 32768: counts bf16 row-major [128][128]
#define OFF_INV  (OFF_AB + 16777216ULL)    // per-graph 512: invdeg f32 [128]
#define WS_NEED  (OFF_INV + 262144ULL)     // 50,724,864 B

typedef __attribute__((ext_vector_type(8))) short short8;
typedef __attribute__((ext_vector_type(4))) short short4v;
typedef __attribute__((ext_vector_type(4))) float f32x4;

__device__ __forceinline__ ushort bf16_rne(float x) {
    unsigned u = __float_as_uint(x);
    u += 0x7FFFu + ((u >> 16) & 1u);
    return (ushort)(u >> 16);
}
__device__ __forceinline__ float bf16f(ushort h) {
    return __uint_as_float(((unsigned)h) << 16);
}

// W = [Wl;Wr] (256x128) -> bf16 hi/lo in B-frag order (K=256: kblock stride 8):
// frag t=(nt*8+ks)*64+lane holds B[k][n], n=nt*16+(lane&15), k=ks*32+8*(lane>>4)+j
__global__ __launch_bounds__(256) void wprep(const float* __restrict__ Wl,
                                             const float* __restrict__ Wr,
                                             ushort* __restrict__ whi,
                                             ushort* __restrict__ wlo) {
    int t = blockIdx.x * 256 + threadIdx.x;
    if (t >= 8 * 8 * 64) return;
    int lane = t & 63, ks = (t >> 6) & 7, nt = t >> 9;
    int n  = nt * 16 + (lane & 15);
    int kb = ks * 32 + 8 * (lane >> 4);
#pragma unroll
    for (int j = 0; j < 8; ++j) {
        int k = kb + j;
        float w = (k < 128) ? Wl[k * 128 + n] : Wr[(k - 128) * 128 + n];
        ushort hi = bf16_rne(w);
        whi[t * 8 + j] = hi;
        wlo[t * 8 + j] = bf16_rne(w - bf16f(hi));
    }
}

// ================= K1: gather emb -> hi/lo planes; count matrix; invdeg ==========
__global__ __launch_bounds__(512) void k1_gather(const int* __restrict__ x_idx,
                                                 const int* __restrict__ edge_index,
                                                 const float* __restrict__ emb,
                                                 char* __restrict__ ws)
{
    __shared__ int acntW[128 * 64];   // ushort-pair count cells packed in int words
    __shared__ int degi[128];
    __shared__ int nid[NNODE];
    const int g = blockIdx.x, tid = threadIdx.x;

    for (int i = tid; i < 128 * 64; i += 512) acntW[i] = 0;
    if (tid < 128) degi[tid] = 0;
    if (tid < NNODE) nid[tid] = x_idx[g * NNODE + tid];
    __syncthreads();

    // edges -> packed ushort counts + degrees (int atomics)
    for (int i = tid; i < EPG; i += 512) {
        int s = edge_index[g * EPG + i] - g * NNODE;
        int d = edge_index[ETOT + g * EPG + i] - g * NNODE;
        atomicAdd(&acntW[d * 64 + (s >> 1)], 1 << (16 * (s & 1)));
        atomicAdd(&degi[d], 1);
    }

    // gather embeddings -> row-major bf16 hi/lo planes (coalesced 16B stores)
    ushort* hhi = (ushort*)(ws + OFF_AHL + (size_t)g * 65536);
    ushort* hlo = hhi + 16384;
    const float4* emb4 = (const float4*)emb;
    for (int i = tid; i < NNODE * 16; i += 512) {
        int n = i >> 4, p = i & 15;
        float4 a = emb4[nid[n] * 32 + 2 * p];
        float4 b = emb4[nid[n] * 32 + 2 * p + 1];
        float vf[8] = {a.x, a.y, a.z, a.w, b.x, b.y, b.z, b.w};
        short8 hh, hl;
#pragma unroll
        for (int j = 0; j < 8; ++j) {
            ushort hb = bf16_rne(vf[j]);
            hh[j] = (short)hb;
            hl[j] = (short)bf16_rne(vf[j] - bf16f(hb));
        }
        *reinterpret_cast<short8*>(&hhi[n * 128 + 8 * p]) = hh;
        *reinterpret_cast<short8*>(&hlo[n * 128 + 8 * p]) = hl;
    }
    // zero pad rows 100..127
    for (int i = tid; i < 28 * 16; i += 512) {
        int n = 100 + (i >> 4), p = i & 15;
        *reinterpret_cast<uint4*>(&hhi[n * 128 + 8 * p]) = uint4{0, 0, 0, 0};
        *reinterpret_cast<uint4*>(&hlo[n * 128 + 8 * p]) = uint4{0, 0, 0, 0};
    }
    __syncthreads();

    // counts -> bf16 row-major (exact: counts small ints), invdeg
    ushort* abf = (ushort*)(ws + OFF_AB + (size_t)g * 32768);
    for (int i = tid; i < 128 * 64; i += 512) {
        int w = acntW[i];
        ushort c0 = bf16_rne((float)(w & 0xFFFF));
        ushort c1 = bf16_rne((float)(((unsigned)w) >> 16));
        ((unsigned*)abf)[i] = (unsigned)c0 | ((unsigned)c1 << 16);
    }
    float* invd = (float*)(ws + OFF_INV + (size_t)g * 512);
    if (tid < 128) invd[tid] = 1.0f / fmaxf((float)degi[tid], 1.0f);
}

// ================= K2: P,Q = h@Wl,h@Wr ; R = Acnt@P ; hnew ======================
__global__ __launch_bounds__(512, 4) void k2_mfma(const float* __restrict__ blv,
                                                  char* __restrict__ ws)
{
    __shared__ ushort pbhi[16384];
    __shared__ ushort pblo[16384];
    const int g = blockIdx.x, tid = threadIdx.x;
    const int lane = tid & 63, wv = tid >> 6;
    const int mgrp = wv >> 1, ngrp = wv & 1;   // mtiles {2mgrp,2mgrp+1}, ntiles {4ngrp..+3}

    const ushort* hhi = (const ushort*)(ws + OFF_AHL + (size_t)g * 65536);
    const ushort* hlo = hhi + 16384;
    const ushort* whi = (const ushort*)ws;
    const ushort* wlo = whi + 32768;
    const ushort* abf = (const ushort*)(ws + OFF_AB + (size_t)g * 32768);
    const float*  invd = (const float*)(ws + OFF_INV + (size_t)g * 512);

    f32x4 accP[2][4], accQ[2][4];
#pragma unroll
    for (int im = 0; im < 2; ++im)
#pragma unroll
        for (int in = 0; in < 4; ++in) {
            accP[im][in] = f32x4{0.f, 0.f, 0.f, 0.f};
            accQ[im][in] = f32x4{0.f, 0.f, 0.f, 0.f};
        }

#pragma unroll
    for (int ks = 0; ks < 4; ++ks) {
        const int kb = ks * 32 + 8 * (lane >> 4);
        short8 Ah[2], Al[2];
#pragma unroll
        for (int im = 0; im < 2; ++im) {
            int m = (2 * mgrp + im) * 16 + (lane & 15);
            Ah[im] = *reinterpret_cast<const short8*>(&hhi[m * 128 + kb]);
            Al[im] = *reinterpret_cast<const short8*>(&hlo[m * 128 + kb]);
        }
#pragma unroll
        for (int in = 0; in < 4; ++in) {
            int nt = 4 * ngrp + in;
            int tL = ((nt * 8 + ks) * 64 + lane) * 8;
            int tR = ((nt * 8 + ks + 4) * 64 + lane) * 8;
            short8 BhL = *reinterpret_cast<const short8*>(whi + tL);
            short8 BlL = *reinterpret_cast<const short8*>(wlo + tL);
            short8 BhR = *reinterpret_cast<const short8*>(whi + tR);
            short8 BlR = *reinterpret_cast<const short8*>(wlo + tR);
#pragma unroll
            for (int im = 0; im < 2; ++im) {
                accP[im][in] = __builtin_amdgcn_mfma_f32_16x16x32_bf16(Ah[im], BhL, accP[im][in], 0, 0, 0);
                accP[im][in] = __builtin_amdgcn_mfma_f32_16x16x32_bf16(Al[im], BhL, accP[im][in], 0, 0, 0);
                accP[im][in] = __builtin_amdgcn_mfma_f32_16x16x32_bf16(Ah[im], BlL, accP[im][in], 0, 0, 0);
                accQ[im][in] = __builtin_amdgcn_mfma_f32_16x16x32_bf16(Ah[im], BhR, accQ[im][in], 0, 0, 0);
                accQ[im][in] = __builtin_amdgcn_mfma_f32_16x16x32_bf16(Al[im], BhR, accQ[im][in], 0, 0, 0);
                accQ[im][in] = __builtin_amdgcn_mfma_f32_16x16x32_bf16(Ah[im], BlR, accQ[im][in], 0, 0, 0);
            }
        }
    }

    // pack P (hi/lo) into LDS B-frag layout (K=128: kblock stride 4)
#pragma unroll
    for (int im = 0; im < 2; ++im) {
        int row0 = (2 * mgrp + im) * 16 + 4 * (lane >> 4);
#pragma unroll
        for (int in = 0; in < 4; ++in) {
            int col = (4 * ngrp + in) * 16 + (lane & 15);
            int idx = ((col >> 4) * 4 + (row0 >> 5)) * 512 +
                      ((col & 15) + 16 * ((row0 >> 3) & 3)) * 8 + (row0 & 7);
            short4v h4, l4;
#pragma unroll
            for (int r = 0; r < 4; ++r) {
                float v = accP[im][in][r];
                ushort hb = bf16_rne(v);
                h4[r] = (short)hb;
                l4[r] = (short)bf16_rne(v - bf16f(hb));
            }
            *reinterpret_cast<short4v*>(&pbhi[idx]) = h4;
            *reinterpret_cast<short4v*>(&pblo[idx]) = l4;
        }
    }
    __syncthreads();   // pack visible; also drains all hhi/hlo global reads

    f32x4 accR[2][4];
#pragma unroll
    for (int im = 0; im < 2; ++im)
#pragma unroll
        for (int in = 0; in < 4; ++in) accR[im][in] = f32x4{0.f, 0.f, 0.f, 0.f};

#pragma unroll
    for (int ks = 0; ks < 4; ++ks) {
        const int kb = ks * 32 + 8 * (lane >> 4);
        short8 Ab[2];
#pragma unroll
        for (int im = 0; im < 2; ++im) {
            int m = (2 * mgrp + im) * 16 + (lane & 15);
            Ab[im] = *reinterpret_cast<const short8*>(&abf[m * 128 + kb]);
        }
#pragma unroll
        for (int in = 0; in < 4; ++in) {
            int fi = (((4 * ngrp + in) * 4 + ks) * 64 + lane) * 8;
            short8 Bh = *reinterpret_cast<const short8*>(&pbhi[fi]);
            short8 Bl = *reinterpret_cast<const short8*>(&pblo[fi]);
#pragma unroll
            for (int im = 0; im < 2; ++im) {
                accR[im][in] = __builtin_amdgcn_mfma_f32_16x16x32_bf16(Ab[im], Bh, accR[im][in], 0, 0, 0);
                accR[im][in] = __builtin_amdgcn_mfma_f32_16x16x32_bf16(Ab[im], Bl, accR[im][in], 0, 0, 0);
            }
        }
    }

    // hnew = relu(R*invd + Q + bl) -> overlay h-plane region (reads drained above)
    float* hnew = (float*)(ws + OFF_AHL + (size_t)g * 65536);
#pragma unroll
    for (int im = 0; im < 2; ++im) {
        int rbase = (2 * mgrp + im) * 16 + 4 * (lane >> 4);
#pragma unroll
        for (int r = 0; r < 4; ++r) {
            int row = rbase + r;
            if (row < NNODE) {
                float iv = invd[row];
#pragma unroll
                for (int in = 0; in < 4; ++in) {
                    int col = (4 * ngrp + in) * 16 + (lane & 15);
                    float v = fmaxf(accR[im][in][r] * iv + accQ[im][in][r] + blv[col], 0.0f);
                    hnew[row * 128 + col] = v;
                }
            }
        }
    }
}

// ================= K3: pooling scores, ranks, readout, MLP ======================
__global__ __launch_bounds__(256) void k3_pool(const float* __restrict__ pw1,
                                               const float* __restrict__ pw2,
                                               const float* __restrict__ W1,
                                               const float* __restrict__ b1g,
                                               const float* __restrict__ W3,
                                               const float* __restrict__ b3g,
                                               const char* __restrict__ ws,
                                               float* __restrict__ out)
{
    __shared__ float score1[NNODE], q2s[NNODE], s2v[NNODE];
    __shared__ int   rank1[NNODE], rank2[NNODE];
    __shared__ float redm1[2][DIM], reds1[2][DIM], redm2[2][DIM], reds2[2][DIM];
    __shared__ float xv[2 * DIM];
    __shared__ float part[4][64];

    const int g = blockIdx.x, tid = threadIdx.x;
    const int lane = tid & 63, wv = tid >> 6;
    const float* hnew = (const float*)(ws + OFF_AHL + (size_t)g * 65536);

    // scores
    {
        float a1 = pw1[lane], c1 = pw1[lane + 64];
        float a2 = pw2[lane], c2 = pw2[lane + 64];
        float n1 = a1 * a1 + c1 * c1;
        float n2 = a2 * a2 + c2 * c2;
#pragma unroll
        for (int off = 32; off; off >>= 1) {
            n1 += __shfl_xor(n1, off);
            n2 += __shfl_xor(n2, off);
        }
        float rn1 = 1.0f / sqrtf(n1);
        float rn2 = 1.0f / sqrtf(n2);
        for (int n = wv; n < NNODE; n += 4) {
            float hA = hnew[n * 128 + lane], hB = hnew[n * 128 + lane + 64];
            float d1 = hA * a1 + hB * c1;
            float d2 = hA * a2 + hB * c2;
#pragma unroll
            for (int off = 32; off; off >>= 1) {
                d1 += __shfl_xor(d1, off);
                d2 += __shfl_xor(d2, off);
            }
            if (lane == 0) {
                score1[n] = tanhf(d1 * rn1);
                q2s[n]    = d2 * rn2;
            }
        }
    }
    __syncthreads();

    // rank1 + s2v
    if (tid < NNODE) {
        float si = score1[tid];
        int r = 0;
        for (int j = 0; j < NNODE; ++j) {
            float sj = score1[j];
            r += (sj > si || (sj == si && j < tid)) ? 1 : 0;
        }
        rank1[tid] = r;
        s2v[tid] = tanhf(score1[tid] * q2s[tid]);
    }
    __syncthreads();

    // rank2 among selected
    if (tid < NNODE) {
        int r1i = rank1[tid];
        if (r1i < K1) {
            float si = s2v[tid];
            int r = 0;
            for (int j = 0; j < NNODE; ++j) {
                if (rank1[j] < K1) {
                    float sj = s2v[j];
                    r += (sj > si || (sj == si && rank1[j] < r1i)) ? 1 : 0;
                }
            }
            rank2[tid] = r;
        } else {
            rank2[tid] = 1 << 30;
        }
    }
    __syncthreads();

    // readout
    {
        int f = tid & 127;
        int c = tid >> 7;   // 0..1
        float mx1 = -INFINITY, sm1 = 0.0f, mx2 = -INFINITY, sm2 = 0.0f;
        for (int n = c; n < NNODE; n += 2) {
            if (rank1[n] < K1) {
                float v1 = hnew[n * 128 + f] * score1[n];
                mx1 = fmaxf(mx1, v1);
                sm1 += v1;
                if (rank2[n] < K2) {
                    float v2 = v1 * s2v[n];
                    mx2 = fmaxf(mx2, v2);
                    sm2 += v2;
                }
            }
        }
        redm1[c][f] = mx1; reds1[c][f] = sm1;
        redm2[c][f] = mx2; reds2[c][f] = sm2;
    }
    __syncthreads();
    if (tid < DIM) {
        float m1 = fmaxf(redm1[0][tid], redm1[1][tid]);
        float s1 = reds1[0][tid] + reds1[1][tid];
        float m2 = fmaxf(redm2[0][tid], redm2[1][tid]);
        float s2 = reds2[0][tid] + reds2[1][tid];
        xv[tid]       = m1 + m2;
        xv[DIM + tid] = s1 * (1.0f / K1) + s2 * (1.0f / K2);
    }
    __syncthreads();

    // MLP head
    {
        int o = tid & 63, ch = tid >> 6;  // ch 0..3
        float acc = 0.0f;
#pragma unroll 8
        for (int u = 0; u < 64; ++u) {
            int fi = ch * 64 + u;
            acc += xv[fi] * W1[fi * 64 + o];
        }
        part[ch][o] = acc;
        __syncthreads();
        if (tid < 64) {
            float a2 = b1g[tid] + part[0][tid] + part[1][tid] + part[2][tid] + part[3][tid];
            float y = fmaxf(a2, 0.0f);
            float r = y * W3[tid];
#pragma unroll
            for (int off = 32; off; off >>= 1) r += __shfl_xor(r, off);
            if (tid == 0) out[g] = 1.0f / (1.0f + expf(-(r + b3g[0])));
        }
    }
}

// ================= fallback monolith (round-7, proven) ==========================
__global__ __launch_bounds__(1024) void fused_gnn(
    const int*   __restrict__ x_idx,
    const int*   __restrict__ edge_index,
    const float* __restrict__ emb,
    const float* __restrict__ blv,
    const float* __restrict__ pw1,
    const float* __restrict__ pw2,
    const float* __restrict__ W1,
    const float* __restrict__ b1g,
    const float* __restrict__ W3,
    const float* __restrict__ b3g,
    const ushort* __restrict__ whi,
    const ushort* __restrict__ wlo,
    float*       __restrict__ out)
{
    __shared__ __align__(16) float Xf[128 * PAD];
    __shared__ __align__(16) int   Zi[128 * PAD];
    __shared__ int degi[NNODE];
    __shared__ int nid[NNODE];
    __shared__ float score1[NNODE], q2[NNODE], s2v[NNODE];
    __shared__ int   rank1[NNODE], rank2[NNODE];
    __shared__ float xv[2 * DIM];

    const int g    = blockIdx.x;
    const int tid  = threadIdx.x;
    const int lane = tid & 63;
    const int wv   = tid >> 6;
    const int mg = wv >> 2, ng = wv & 3;

    {
        int4* z4 = reinterpret_cast<int4*>(Zi);
        for (int i = tid; i < 128 * PAD / 4; i += 1024) z4[i] = int4{0, 0, 0, 0};
        float4* xz = reinterpret_cast<float4*>(Xf + 100 * PAD);
        for (int i = tid; i < 28 * PAD / 4; i += 1024) xz[i] = float4{0, 0, 0, 0};
        if (tid < NNODE) { nid[tid] = x_idx[g * NNODE + tid]; degi[tid] = 0; }
    }
    __syncthreads();
    {
        const float4* emb4 = reinterpret_cast<const float4*>(emb);
        for (int i = tid; i < NNODE * 32; i += 1024) {
            int n = i >> 5, q = i & 31;
            float4 v = emb4[nid[n] * 32 + q];
            *reinterpret_cast<float4*>(&Xf[n * PAD + q * 4]) = v;
        }
        for (int i = tid; i < EPG; i += 1024) {
            int s = edge_index[g * EPG + i] - g * NNODE;
            int d = edge_index[ETOT + g * EPG + i] - g * NNODE;
            atomicAdd(&Zi[d * PAD + s], 1);
            atomicAdd(&degi[d], 1);
        }
    }
    __syncthreads();

    ushort* ahhi = reinterpret_cast<ushort*>(Xf);
    ushort* ahlo = ahhi + 16384;
    ushort* abf  = reinterpret_cast<ushort*>(Zi);

    {
        const int m  = tid >> 3;
        const int kb = (tid & 7) * 16;
        float hv[16];
        int   cv[16];
#pragma unroll
        for (int u = 0; u < 4; ++u) {
            float4 v = *reinterpret_cast<const float4*>(&Xf[m * PAD + kb + 4 * u]);
            hv[4 * u] = v.x; hv[4 * u + 1] = v.y; hv[4 * u + 2] = v.z; hv[4 * u + 3] = v.w;
            int4 c = *reinterpret_cast<const int4*>(&Zi[m * PAD + kb + 4 * u]);
            cv[4 * u] = c.x; cv[4 * u + 1] = c.y; cv[4 * u + 2] = c.z; cv[4 * u + 3] = c.w;
        }
        __syncthreads();
#pragma unroll
        for (int g2 = 0; g2 < 2; ++g2) {
            int idx = ((m >> 4) * 4 + (kb >> 5)) * 512 +
                      ((m & 15) + 16 * (((kb >> 3) + g2) & 3)) * 8;
            short8 hh, hl, ab;
#pragma unroll
            for (int j = 0; j < 8; ++j) {
                float v = hv[g2 * 8 + j];
                ushort hb = bf16_rne(v);
                hh[j] = (short)hb;
                hl[j] = (short)bf16_rne(v - bf16f(hb));
                ab[j] = (short)bf16_rne((float)cv[g2 * 8 + j]);
            }
            *reinterpret_cast<short8*>(&ahhi[idx]) = hh;
            *reinterpret_cast<short8*>(&ahlo[idx]) = hl;
            *reinterpret_cast<short8*>(&abf[idx])  = ab;
        }
    }
    __syncthreads();

    f32x4 accP[2][2], accQ[2][2];
#pragma unroll
    for (int im = 0; im < 2; ++im)
#pragma unroll
        for (int in = 0; in < 2; ++in) {
            accP[im][in] = f32x4{0.f, 0.f, 0.f, 0.f};
            accQ[im][in] = f32x4{0.f, 0.f, 0.f, 0.f};
        }
#pragma unroll
    for (int ks = 0; ks < 4; ++ks) {
        short8 Ah[2], Al[2];
#pragma unroll
        for (int im = 0; im < 2; ++im) {
            int fi = (((2 * mg + im) * 4 + ks) * 64 + lane) * 8;
            Ah[im] = *reinterpret_cast<const short8*>(&ahhi[fi]);
            Al[im] = *reinterpret_cast<const short8*>(&ahlo[fi]);
        }
        short8 BhL[2], BlL[2], BhR[2], BlR[2];
#pragma unroll
        for (int in = 0; in < 2; ++in) {
            int nt = 2 * ng + in;
            int tL = ((nt * 8 + ks) * 64 + lane) * 8;
            int tR = ((nt * 8 + ks + 4) * 64 + lane) * 8;
            BhL[in] = *reinterpret_cast<const short8*>(whi + tL);
            BlL[in] = *reinterpret_cast<const short8*>(wlo + tL);
            BhR[in] = *reinterpret_cast<const short8*>(whi + tR);
            BlR[in] = *reinterpret_cast<const short8*>(wlo + tR);
        }
#pragma unroll
        for (int im = 0; im < 2; ++im)
#pragma unroll
            for (int in = 0; in < 2; ++in) {
                accP[im][in] = __builtin_amdgcn_mfma_f32_16x16x32_bf16(Ah[im], BhL[in], accP[im][in], 0, 0, 0);
                accP[im][in] = __builtin_amdgcn_mfma_f32_16x16x32_bf16(Al[im], BhL[in], accP[im][in], 0, 0, 0);
                accP[im][in] = __builtin_amdgcn_mfma_f32_16x16x32_bf16(Ah[im], BlL[in], accP[im][in], 0, 0, 0);
                accQ[im][in] = __builtin_amdgcn_mfma_f32_16x16x32_bf16(Ah[im], BhR[in], accQ[im][in], 0, 0, 0);
                accQ[im][in] = __builtin_amdgcn_mfma_f32_16x16x32_bf16(Al[im], BhR[in], accQ[im][in], 0, 0, 0);
                accQ[im][in] = __builtin_amdgcn_mfma_f32_16x16x32_bf16(Ah[im], BlR[in], accQ[im][in], 0, 0, 0);
            }
    }
    __syncthreads();
    {
        ushort* pbhi = ahhi;
        ushort* pblo = ahlo;
#pragma unroll
        for (int im = 0; im < 2; ++im) {
            int row0 = (2 * mg + im) * 16 + 4 * (lane >> 4);
#pragma unroll
            for (int in = 0; in < 2; ++in) {
                int col = (2 * ng + in) * 16 + (lane & 15);
                int idx = ((col >> 4) * 4 + (row0 >> 5)) * 512 +
                          ((col & 15) + 16 * ((row0 >> 3) & 3)) * 8 + (row0 & 7);
                short4v h4, l4;
#pragma unroll
                for (int r = 0; r < 4; ++r) {
                    float v = accP[im][in][r];
                    ushort hb = bf16_rne(v);
                    h4[r] = (short)hb;
                    l4[r] = (short)bf16_rne(v - bf16f(hb));
                }
                *reinterpret_cast<short4v*>(&pbhi[idx]) = h4;
                *reinterpret_cast<short4v*>(&pblo[idx]) = l4;
            }
        }
    }
    __syncthreads();

    f32x4 accR[2][2];
#pragma unroll
    for (int im = 0; im < 2; ++im)
#pragma unroll
        for (int in = 0; in < 2; ++in) accR[im][in] = f32x4{0.f, 0.f, 0.f, 0.f};
#pragma unroll
    for (int ks = 0; ks < 4; ++ks) {
        short8 Ab[2];
#pragma unroll
        for (int im = 0; im < 2; ++im)
            Ab[im] = *reinterpret_cast<const short8*>(&abf[(((2 * mg + im) * 4 + ks) * 64 + lane) * 8]);
        short8 Bh[2], Bl[2];
#pragma unroll
        for (int in = 0; in < 2; ++in) {
            int fi = (((2 * ng + in) * 4 + ks) * 64 + lane) * 8;
            Bh[in] = *reinterpret_cast<const short8*>(&ahhi[fi]);
            Bl[in] = *reinterpret_cast<const short8*>(&ahlo[fi]);
        }
#pragma unroll
        for (int im = 0; im < 2; ++im)
#pragma unroll
            for (int in = 0; in < 2; ++in) {
                accR[im][in] = __builtin_amdgcn_mfma_f32_16x16x32_bf16(Ab[im], Bh[in], accR[im][in], 0, 0, 0);
                accR[im][in] = __builtin_amdgcn_mfma_f32_16x16x32_bf16(Ab[im], Bl[in], accR[im][in], 0, 0, 0);
            }
    }
    __syncthreads();
#pragma unroll
    for (int im = 0; im < 2; ++im) {
        int rbase = (2 * mg + im) * 16 + 4 * (lane >> 4);
#pragma unroll
        for (int in = 0; in < 2; ++in) {
            int col = (2 * ng + in) * 16 + (lane & 15);
            float bc = blv[col];
#pragma unroll
            for (int r = 0; r < 4; ++r) {
                int row = rbase + r;
                if (row < NNODE) {
                    float invd = 1.0f / fmaxf((float)degi[row], 1.0f);
                    Xf[row * PAD + col] = fmaxf(accR[im][in][r] * invd + accQ[im][in][r] + bc, 0.0f);
                }
            }
        }
    }
    __syncthreads();
    {
        float a1 = pw1[lane], c1 = pw1[lane + 64];
        float a2 = pw2[lane], c2 = pw2[lane + 64];
        float n1 = a1 * a1 + c1 * c1;
        float n2 = a2 * a2 + c2 * c2;
#pragma unroll
        for (int off = 32; off; off >>= 1) {
            n1 += __shfl_xor(n1, off);
            n2 += __shfl_xor(n2, off);
        }
        float rn1 = 1.0f / sqrtf(n1);
        float rn2 = 1.0f / sqrtf(n2);
        for (int n = wv; n < NNODE; n += 16) {
            float hA = Xf[n * PAD + lane], hB = Xf[n * PAD + lane + 64];
            float d1 = hA * a1 + hB * c1;
            float d2 = hA * a2 + hB * c2;
#pragma unroll
            for (int off = 32; off; off >>= 1) {
                d1 += __shfl_xor(d1, off);
                d2 += __shfl_xor(d2, off);
            }
            if (lane == 0) {
                score1[n] = tanhf(d1 * rn1);
                q2[n]     = d2 * rn2;
            }
        }
    }
    __syncthreads();
    if (tid < NNODE) {
        float si = score1[tid];
        int r = 0;
        for (int j = 0; j < NNODE; ++j) {
            float sj = score1[j];
            r += (sj > si || (sj == si && j < tid)) ? 1 : 0;
        }
        rank1[tid] = r;
        s2v[tid] = tanhf(score1[tid] * q2[tid]);
    }
    __syncthreads();
    if (tid < NNODE) {
        int r1i = rank1[tid];
        if (r1i < K1) {
            float si = s2v[tid];
            int r = 0;
            for (int j = 0; j < NNODE; ++j) {
                if (rank1[j] < K1) {
                    float sj = s2v[j];
                    r += (sj > si || (sj == si && rank1[j] < r1i)) ? 1 : 0;
                }
            }
            rank2[tid] = r;
        } else {
            rank2[tid] = 1 << 30;
        }
    }
    __syncthreads();
    {
        float* Zf = reinterpret_cast<float*>(Zi);
        float* redm1 = Zf;
        float* reds1 = Zf + 1024;
        float* redm2 = Zf + 2048;
        float* reds2 = Zf + 3072;
        int f = tid & 127;
        int c = tid >> 7;
        float mx1 = -INFINITY, sm1 = 0.0f, mx2 = -INFINITY, sm2 = 0.0f;
        for (int n = c; n < NNODE; n += 8) {
            if (rank1[n] < K1) {
                float v1 = Xf[n * PAD + f] * score1[n];
                mx1 = fmaxf(mx1, v1);
                sm1 += v1;
                if (rank2[n] < K2) {
                    float v2 = v1 * s2v[n];
                    mx2 = fmaxf(mx2, v2);
                    sm2 += v2;
                }
            }
        }
        redm1[c * DIM + f] = mx1; reds1[c * DIM + f] = sm1;
        redm2[c * DIM + f] = mx2; reds2[c * DIM + f] = sm2;
        __syncthreads();
        if (tid < DIM) {
            float m1 = -INFINITY, s1 = 0.0f, m2 = -INFINITY, s2 = 0.0f;
#pragma unroll
            for (int cc = 0; cc < 8; ++cc) {
                m1 = fmaxf(m1, redm1[cc * DIM + tid]); s1 += reds1[cc * DIM + tid];
                m2 = fmaxf(m2, redm2[cc * DIM + tid]); s2 += reds2[cc * DIM + tid];
            }
            xv[tid]       = m1 + m2;
            xv[DIM + tid] = s1 * (1.0f / K1) + s2 * (1.0f / K2);
        }
    }
    __syncthreads();
    {
        float* Zf = reinterpret_cast<float*>(Zi);
        float* part = Zf + 4096;
        int o = tid & 63, ch = tid >> 6;
        float acc = 0.0f;
#pragma unroll
        for (int u = 0; u < 16; ++u) {
            int f = ch * 16 + u;
            acc += xv[f] * W1[f * 64 + o];
        }
        part[ch * 64 + o] = acc;
        __syncthreads();
        if (tid < 64) {
            float a2 = b1g[tid];
#pragma unroll
            for (int cc = 0; cc < 16; ++cc) a2 += part[cc * 64 + tid];
            float y = fmaxf(a2, 0.0f);
            float r = y * W3[tid];
#pragma unroll
            for (int off = 32; off; off >>= 1) r += __shfl_xor(r, off);
            if (tid == 0) out[g] = 1.0f / (1.0f + expf(-(r + b3g[0])));
        }
    }
}

extern "C" void kernel_launch(void* const* d_in, const int* in_sizes, int n_in,
                              void* d_out, int out_size, void* d_ws, size_t ws_size,
                              hipStream_t stream) {
    const int*   x_idx      = (const int*)d_in[0];
    const int*   edge_index = (const int*)d_in[1];
    const float* emb = (const float*)d_in[3];
    const float* Wl  = (const float*)d_in[4];
    const float* bl  = (const float*)d_in[5];
    const float* Wr  = (const float*)d_in[6];
    const float* pw1 = (const float*)d_in[7];
    const float* pw2 = (const float*)d_in[8];
    const float* W1  = (const float*)d_in[9];
    const float* b1  = (const float*)d_in[10];
    const float* W3  = (const float*)d_in[11];
    const float* b3  = (const float*)d_in[12];
    float* out = (float*)d_out;

    ushort* whi = (ushort*)d_ws;
    ushort* wlo = (ushort*)((char*)d_ws + 65536);

    wprep<<<16, 256, 0, stream>>>(Wl, Wr, whi, wlo);

    if (ws_size >= (size_t)WS_NEED) {
        k1_gather<<<BGRAPH, 512, 0, stream>>>(x_idx, edge_index, emb, (char*)d_ws);
        k2_mfma<<<BGRAPH, 512, 0, stream>>>(bl, (char*)d_ws);
        k3_pool<<<BGRAPH, 256, 0, stream>>>(pw1, pw2, W1, b1, W3, b3, (const char*)d_ws, out);
    } else {
        fused_gnn<<<BGRAPH, 1024, 0, stream>>>(
            x_idx, edge_index, emb, bl, pw1, pw2, W1, b1, W3, b3, whi, wlo, out);
    }
}